// Round 3
// baseline (263.053 us; speedup 1.0000x reference)
//
#include <hip/hip_runtime.h>

#define B_ 4
#define N_ 4096
#define H_ 256
#define L2E 1.44269504088896340736f

typedef _Float16 f16;
typedef f16 f16x8 __attribute__((ext_vector_type(8)));
typedef f16 f16x4 __attribute__((ext_vector_type(4)));
typedef float f32x4 __attribute__((ext_vector_type(4)));

static __device__ __forceinline__ f32x4 mfma16(f16x8 a, f16x8 b, f32x4 c){
  return __builtin_amdgcn_mfma_f32_16x16x32_f16(a, b, c, 0, 0, 0);
}

// async global->LDS, 16B per lane; LDS dest is wave-uniform base + lane*16
static __device__ __forceinline__ void gload16(const void* g, void* l){
  __builtin_amdgcn_global_load_lds(
    (const __attribute__((address_space(1))) unsigned int*)g,
    (__attribute__((address_space(3))) unsigned int*)l, 16, 0, 0);
}

static __device__ __forceinline__ f16x8 ldcvt8(const float* __restrict__ p){
  float4 f0 = *(const float4*)p;
  float4 f1 = *(const float4*)(p + 4);
  f16x8 o;
  o[0]=(f16)f0.x; o[1]=(f16)f0.y; o[2]=(f16)f0.z; o[3]=(f16)f0.w;
  o[4]=(f16)f1.x; o[5]=(f16)f1.y; o[6]=(f16)f1.z; o[7]=(f16)f1.w;
  return o;
}

// Fused QKV projection, f32 inputs (inline cvt), f16 outputs.
// Yq,Yk row-major [B*N][H]; Yvt transposed per batch [B][H][N].
__global__ __launch_bounds__(256, 4) void proj_fused(
    const float* __restrict__ X,
    const float* __restrict__ Wq, const float* __restrict__ bq,
    const float* __restrict__ Wk, const float* __restrict__ bk,
    const float* __restrict__ Wv, const float* __restrict__ bv,
    f16* __restrict__ Yq, f16* __restrict__ Yk, f16* __restrict__ Yvt){
  const int tid = threadIdx.x, l = tid & 63, w = tid >> 6;
  const int lr = l & 15, lg = l >> 4;
  const int m0 = blockIdx.x * 64 + w * 16;   // this wave's 16 rows
  const int o0 = blockIdx.y * 64;            // 64 output cols
  f32x4 aq[4] = {{0,0,0,0},{0,0,0,0},{0,0,0,0},{0,0,0,0}};
  f32x4 ak[4] = {{0,0,0,0},{0,0,0,0},{0,0,0,0},{0,0,0,0}};
  f32x4 av[4] = {{0,0,0,0},{0,0,0,0},{0,0,0,0},{0,0,0,0}};
  const float* xp  = X  + (size_t)(m0 + lr) * H_ + lg * 8;
  const float* wqp = Wq + (size_t)(o0 + lr) * H_ + lg * 8;
  const float* wkp = Wk + (size_t)(o0 + lr) * H_ + lg * 8;
  const float* wvp = Wv + (size_t)(o0 + lr) * H_ + lg * 8;
  #pragma unroll
  for (int ks = 0; ks < 8; ++ks){
    f16x8 a = ldcvt8(xp + ks * 32);
    #pragma unroll
    for (int ct = 0; ct < 4; ++ct){
      size_t off = (size_t)(ct*16) * H_ + ks * 32;
      aq[ct] = mfma16(a, ldcvt8(wqp + off), aq[ct]);
      ak[ct] = mfma16(a, ldcvt8(wkp + off), ak[ct]);
      av[ct] = mfma16(a, ldcvt8(wvp + off), av[ct]);
    }
  }
  // q, k: row-major
  #pragma unroll
  for (int ct = 0; ct < 4; ++ct){
    float bvq = bq[o0 + ct*16 + lr];
    float bvk = bk[o0 + ct*16 + lr];
    #pragma unroll
    for (int r = 0; r < 4; ++r){
      size_t idx = (size_t)(m0 + lg*4 + r) * H_ + o0 + ct*16 + lr;
      Yq[idx] = (f16)(aq[ct][r] + bvq);
      Yk[idx] = (f16)(ak[ct][r] + bvk);
    }
  }
  // v: transposed per batch [b][o][n]
  {
    const int b  = m0 >> 12;
    const int n0 = (m0 & (N_-1)) + lg*4;
    #pragma unroll
    for (int ct = 0; ct < 4; ++ct){
      float bvv = bv[o0 + ct*16 + lr];
      int o = o0 + ct*16 + lr;
      f16x4 pk;
      pk[0] = (f16)(av[ct][0] + bvv);
      pk[1] = (f16)(av[ct][1] + bvv);
      pk[2] = (f16)(av[ct][2] + bvv);
      pk[3] = (f16)(av[ct][3] + bvv);
      *(f16x4*)(Yvt + ((size_t)(b * H_ + o)) * N_ + n0) = pk;
    }
  }
}

// Flash attention: 1 block = (batch b, 64 q-rows); 8 waves (512 threads).
// Waves 0-3 (group A) handle kv cols 0-31 of each tile, waves 4-7 (group B)
// cols 32-63; wave w handles q rows (w&3)*16..+15. Each group keeps its own
// online (m,l,O); groups merge at the end via LDS (split-kv merge).
__global__ __launch_bounds__(512, 2) void flash_kernel(
    const f16* __restrict__ Q, const f16* __restrict__ K,
    const f16* __restrict__ Vt, float* __restrict__ O){
  __shared__ f16 Kl[2][64*256];   // 32KB x2, row = 512B = 32 chunks
  __shared__ f16 Vl[2][256*64];   // 32KB x2, row = 128B = 8 chunks
  __shared__ f16 Pl[8][16*40];    // per-wave P (16q x 32kv), stride 40 (80B)
  const int tid = threadIdx.x, l = tid & 63, w = tid >> 6;
  const int lr = l & 15, lg = l >> 4;
  const int g  = w >> 2;          // kv-half group
  const int wq = w & 3;           // q-row sub-tile
  const int b = blockIdx.x >> 6, qt = blockIdx.x & 63;
  const int q0 = qt * 64;
  const f16* Kg = K  + (size_t)b * N_ * H_;
  const f16* Vg = Vt + (size_t)b * H_ * N_;

  // hoist Q fragments (16 rows x 256 k-dim = 8 A-frags)
  f16x8 qf[8];
  {
    const f16* qp = Q + ((size_t)b * N_ + q0 + wq*16 + lr) * H_ + lg*8;
    #pragma unroll
    for (int ks = 0; ks < 8; ++ks) qf[ks] = *(const f16x8*)(qp + ks*32);
  }

  f32x4 oacc[16];
  #pragma unroll
  for (int ft = 0; ft < 16; ++ft) oacc[ft] = {0.f,0.f,0.f,0.f};
  float m_run[4], l_run[4];
  #pragma unroll
  for (int r = 0; r < 4; ++r){ m_run[r] = -3.0e38f; l_run[r] = 0.f; }

  auto stage = [&](int buf, int t){
    const int kv0 = t * 64;
    #pragma unroll
    for (int i = 0; i < 4; ++i){          // K: 2048 16B chunks / 512 threads
      int c = i*512 + tid;
      int r = c >> 5, x = c & 31;         // row, chunk-in-row
      gload16(Kg + (size_t)(kv0 + r)*H_ + ((x ^ (r & 7)) << 3),
              &Kl[buf][(i*512 + (tid & ~63)) * 8]);
    }
    #pragma unroll
    for (int i = 0; i < 4; ++i){          // Vt: 2048 16B chunks
      int c = i*512 + tid;
      int f = c >> 3, x = c & 7;
      gload16(Vg + (size_t)f*N_ + kv0 + ((x ^ (f & 7)) << 3),
              &Vl[buf][(i*512 + (tid & ~63)) * 8]);
    }
  };

  stage(0, 0);
  __syncthreads();

  for (int t = 0; t < 64; ++t){
    const int cur = t & 1;
    if (t + 1 < 64) stage(cur ^ 1, t + 1);   // prefetch next tile

    // ---- S = Q K^T : 16q x 32kv (this group's half)
    f32x4 s[2];
    s[0] = {0.f,0.f,0.f,0.f}; s[1] = {0.f,0.f,0.f,0.f};
    const char* Kb = (const char*)Kl[cur];
    __builtin_amdgcn_s_setprio(1);
    #pragma unroll
    for (int ks = 0; ks < 8; ++ks){
      #pragma unroll
      for (int ct = 0; ct < 2; ++ct){
        const int n  = g*32 + ct*16 + lr;   // kv row
        const int cw = ks*4 + lg;           // wanted 16B chunk
        f16x8 bf = *(const f16x8*)(Kb + n*512 + ((cw ^ (n & 7)) << 4));
        s[ct] = mfma16(qf[ks], bf, s[ct]);
      }
    }
    __builtin_amdgcn_s_setprio(0);

    // ---- online softmax (rows = lg*4+r, cols over 16 lanes x 2 ct)
    float mx[4];
    #pragma unroll
    for (int r = 0; r < 4; ++r) mx[r] = fmaxf(s[0][r], s[1][r]);
    #pragma unroll
    for (int d = 1; d < 16; d <<= 1)
      #pragma unroll
      for (int r = 0; r < 4; ++r) mx[r] = fmaxf(mx[r], __shfl_xor(mx[r], d));

    float need = mx[0] - m_run[0];
    #pragma unroll
    for (int r = 1; r < 4; ++r) need = fmaxf(need, mx[r] - m_run[r]);
    if (!__all(need <= 8.0f)){
      // full rescale path
      float al[4];
      #pragma unroll
      for (int r = 0; r < 4; ++r){
        float mn = fmaxf(m_run[r], mx[r]);
        al[r] = __builtin_amdgcn_exp2f((m_run[r] - mn) * L2E);
        m_run[r] = mn;
      }
      #pragma unroll
      for (int r = 0; r < 4; ++r) l_run[r] *= al[r];
      #pragma unroll
      for (int ft = 0; ft < 16; ++ft)
        #pragma unroll
        for (int r = 0; r < 4; ++r) oacc[ft][r] *= al[r];
    }
    float ps[4] = {0.f,0.f,0.f,0.f};
    #pragma unroll
    for (int ct = 0; ct < 2; ++ct)
      #pragma unroll
      for (int r = 0; r < 4; ++r){
        float p = __builtin_amdgcn_exp2f((s[ct][r] - m_run[r]) * L2E);
        s[ct][r] = p;
        ps[r] += p;
      }
    #pragma unroll
    for (int d = 1; d < 16; d <<= 1)
      #pragma unroll
      for (int r = 0; r < 4; ++r) ps[r] += __shfl_xor(ps[r], d);
    #pragma unroll
    for (int r = 0; r < 4; ++r) l_run[r] += ps[r];

    // ---- P (C-layout) -> per-wave LDS -> A-frag layout
    f16* Pw = Pl[w];
    #pragma unroll
    for (int ct = 0; ct < 2; ++ct)
      #pragma unroll
      for (int r = 0; r < 4; ++r)
        Pw[(lg*4 + r)*40 + ct*16 + lr] = (f16)s[ct][r];

    // ---- O += P V   (K=32 over this group's kv half)
    const char* Vb = (const char*)Vl[cur];
    const char* Pb = (const char*)Pw;
    f16x8 af = *(const f16x8*)(Pb + lr*80 + lg*16);
    __builtin_amdgcn_s_setprio(1);
    #pragma unroll
    for (int ft = 0; ft < 16; ++ft){
      const int f  = ft*16 + lr;
      const int cw = g*4 + lg;
      f16x8 bf = *(const f16x8*)(Vb + f*128 + ((cw ^ (f & 7)) << 4));
      oacc[ft] = mfma16(af, bf, oacc[ft]);
    }
    __builtin_amdgcn_s_setprio(0);
    __syncthreads();   // drains vmcnt(0): next-tile stage complete
  }

  // ---- merge group B into group A via LDS
  __syncthreads();
  float* Lf = (float*)&Kl[0][0];           // 64KB scratch = 16384 floats
  float* ml = (float*)&Pl[0][0];           // m/l scratch
  if (g == 1){
    float* dst = Lf + wq * 4096;
    #pragma unroll
    for (int ft = 0; ft < 16; ++ft)
      #pragma unroll
      for (int r = 0; r < 4; ++r)
        dst[(lg*4 + r)*256 + ft*16 + lr] = oacc[ft][r];
    if (lr == 0){
      #pragma unroll
      for (int r = 0; r < 4; ++r){
        ml[wq*16 + lg*4 + r]       = m_run[r];
        ml[64 + wq*16 + lg*4 + r]  = l_run[r];
      }
    }
  }
  __syncthreads();
  if (g == 0){
    const float* src = Lf + wq * 4096;
    float eA[4], eB[4], inv[4];
    #pragma unroll
    for (int r = 0; r < 4; ++r){
      float mB = ml[wq*16 + lg*4 + r];
      float lB = ml[64 + wq*16 + lg*4 + r];
      float ms = fmaxf(m_run[r], mB);
      eA[r] = __builtin_amdgcn_exp2f((m_run[r] - ms) * L2E);
      eB[r] = __builtin_amdgcn_exp2f((mB - ms) * L2E);
      inv[r] = 1.0f / (eA[r]*l_run[r] + eB[r]*lB);
    }
    float* Ob = O + ((size_t)b * N_ + q0 + wq*16) * H_;
    #pragma unroll
    for (int ft = 0; ft < 16; ++ft)
      #pragma unroll
      for (int r = 0; r < 4; ++r){
        float ob = src[(lg*4 + r)*256 + ft*16 + lr];
        Ob[(size_t)(lg*4 + r) * H_ + ft*16 + lr] =
          (eA[r]*oacc[ft][r] + eB[r]*ob) * inv[r];
      }
  }
}

extern "C" void kernel_launch(void* const* d_in, const int* in_sizes, int n_in,
                              void* d_out, int out_size, void* d_ws, size_t ws_size,
                              hipStream_t stream) {
  const float* x  = (const float*)d_in[0];
  const float* Wq = (const float*)d_in[1];
  const float* bq = (const float*)d_in[2];
  const float* Wk = (const float*)d_in[3];
  const float* bk = (const float*)d_in[4];
  const float* Wv = (const float*)d_in[5];
  const float* bv = (const float*)d_in[6];
  float* out = (float*)d_out;

  // workspace: q, k (row-major), vt (transposed) — 3 x 8MB f16
  char* ws = (char*)d_ws;
  const size_t SZ = (size_t)B_ * N_ * H_ * 2;          // 8,388,608 B
  f16* qb = (f16*)(ws);
  f16* kb = (f16*)(ws + SZ);
  f16* vt = (f16*)(ws + 2*SZ);  // [B][H][N]

  dim3 pgrid(B_*N_/64, H_/64);
  proj_fused<<<pgrid, 256, 0, stream>>>(x, Wq, bq, Wk, bk, Wv, bv, qb, kb, vt);
  flash_kernel<<<B_*(N_/64), 512, 0, stream>>>(qb, kb, vt, out);
}

// Round 5
// 170.645 us; speedup vs baseline: 1.5415x; 1.5415x over previous
//
#include <hip/hip_runtime.h>

#define B_ 4
#define N_ 4096
#define H_ 256
#define BN_ (B_*N_)
#define L2E 1.44269504088896340736f

typedef _Float16 f16;
typedef __fp16 fp16x2 __attribute__((ext_vector_type(2)));
typedef f16 f16x4 __attribute__((ext_vector_type(4)));
typedef f16 f16x8 __attribute__((ext_vector_type(8)));
typedef float f32x4 __attribute__((ext_vector_type(4)));
typedef float f32x16 __attribute__((ext_vector_type(16)));

static __device__ __forceinline__ f32x4 mfma16(f16x8 a, f16x8 b, f32x4 c){
  return __builtin_amdgcn_mfma_f32_16x16x32_f16(a, b, c, 0, 0, 0);
}
static __device__ __forceinline__ f32x16 mfma32(f16x8 a, f16x8 b, f32x16 c){
  return __builtin_amdgcn_mfma_f32_32x32x16_f16(a, b, c, 0, 0, 0);
}
static __device__ __forceinline__ unsigned pkrtz(float a, float b){
  fp16x2 h = __builtin_amdgcn_cvt_pkrtz(a, b);
  return __builtin_bit_cast(unsigned, h);
}

// async global->LDS, 16B per lane; LDS dest is wave-uniform base + lane*16
static __device__ __forceinline__ void gload16(const void* g, void* l){
  __builtin_amdgcn_global_load_lds(
    (const __attribute__((address_space(1))) unsigned int*)g,
    (__attribute__((address_space(3))) unsigned int*)l, 16, 0, 0);
}

__global__ __launch_bounds__(256, 4) void cvt_f32_f16(
    const float* __restrict__ in, f16* __restrict__ out, int n4){
  int i = blockIdx.x * 256 + threadIdx.x;
  if (i < n4){
    float4 f = ((const float4*)in)[i];
    f16x4 o;
    o[0] = (f16)f.x; o[1] = (f16)f.y; o[2] = (f16)f.z; o[3] = (f16)f.w;
    ((f16x4*)out)[i] = o;
  }
}

// Y[m][o] = sum_h X[m][h]*W[o][h] + bias[o]; M=B*N rows. (R2 structure, measured 44us)
// VT==0: Y row-major f16 [M][H].  VT==1: write transposed per batch: Y[b][o][n].
template<int VT>
__global__ __launch_bounds__(256, 4) void proj_kernel(
    const f16* __restrict__ X, const f16* __restrict__ W,
    const float* __restrict__ bias, f16* __restrict__ Y){
  const int tid = threadIdx.x, l = tid & 63, w = tid >> 6;
  const int lr = l & 15, lg = l >> 4;
  const int m0 = blockIdx.x * 64 + w * 16;
  const int o0 = blockIdx.y * 64;
  f32x4 acc[4] = {{0,0,0,0},{0,0,0,0},{0,0,0,0},{0,0,0,0}};
  const f16* xp = X + (size_t)(m0 + lr) * H_ + lg * 8;
  const f16* wp = W + (size_t)(o0 + lr) * H_ + lg * 8;
  #pragma unroll
  for (int ks = 0; ks < 8; ++ks){
    f16x8 a = *(const f16x8*)(xp + ks * 32);
    #pragma unroll
    for (int ct = 0; ct < 4; ++ct){
      f16x8 b = *(const f16x8*)(wp + (size_t)(ct*16) * H_ + ks * 32);
      acc[ct] = mfma16(a, b, acc[ct]);
    }
  }
  if (VT == 0){
    #pragma unroll
    for (int ct = 0; ct < 4; ++ct){
      float bv = bias[o0 + ct*16 + lr];
      #pragma unroll
      for (int r = 0; r < 4; ++r){
        int row = m0 + lg*4 + r;
        Y[(size_t)row * H_ + o0 + ct*16 + lr] = (f16)(acc[ct][r] + bv);
      }
    }
  } else {
    const int b  = m0 >> 12;
    const int n0 = (m0 & (N_-1)) + lg*4;
    #pragma unroll
    for (int ct = 0; ct < 4; ++ct){
      float bv = bias[o0 + ct*16 + lr];
      int o = o0 + ct*16 + lr;
      f16x4 pk;
      pk[0] = (f16)(acc[ct][0] + bv);
      pk[1] = (f16)(acc[ct][1] + bv);
      pk[2] = (f16)(acc[ct][2] + bv);
      pk[3] = (f16)(acc[ct][3] + bv);
      *(f16x4*)(Y + ((size_t)(b * H_ + o)) * N_ + n0) = pk;
    }
  }
}

// Flash attention, 32x32 MFMA, swapped operands, QBLK=128, kv-split x2.
// Block = (q-block of 128 rows, kv-half of 2048). 8 waves = 4 q-strips x 2 kv-halves.
// Wave computes S^T(32kv x 32q) with A=K(LDS), B=Q(regs); then O^T with
// A=V^T(LDS), B=P^T built in-register via cvt_pkrtz + shfl_xor(32).
// Writes normalized f16 partial O + log-sum; merge_kernel combines the 2 kv-splits.
__global__ __launch_bounds__(512, 2) void flash_kernel(
    const f16* __restrict__ Q, const f16* __restrict__ K,
    const f16* __restrict__ Vt, f16* __restrict__ Opn, float* __restrict__ mll){
  __shared__ __align__(16) char lds[132*1024];
  f16* Kl0 = (f16*)lds;                   // [2][64*256]  64KB
  f16* Vl0 = (f16*)(lds + 65536);         // [2][256*64]  64KB
  float* mlb = (float*)(lds + 131072);    // 256 floats

  const int tid = threadIdx.x, l = tid & 63, w = tid >> 6;
  const int q32 = l & 31, hi = l >> 5;
  const int strip = w & 3, kvh = w >> 2;
  const int qblk = blockIdx.x >> 1, kb = blockIdx.x & 1;
  const int b = qblk >> 5, qt = qblk & 31;
  const int q0 = qt * 128;
  const int kvbase = kb * 2048;
  const f16* Kg = K  + (size_t)b * N_ * H_;
  const f16* Vg = Vt + (size_t)b * H_ * N_;

  // hoist Q B-frags: col=lane&31 -> q row, k-chunk = ks*16 + hi*8
  f16x8 qf[16];
  {
    const f16* qp = Q + ((size_t)b*N_ + q0 + strip*32 + q32) * H_ + hi*8;
    #pragma unroll
    for (int ks = 0; ks < 16; ++ks) qf[ks] = *(const f16x8*)(qp + ks*16);
  }

  f32x16 oacc[8];
  #pragma unroll
  for (int ft = 0; ft < 8; ++ft)
    #pragma unroll
    for (int e = 0; e < 16; ++e) oacc[ft][e] = 0.f;
  float m_run = -3.0e38f, l_run = 0.f;

  auto stage = [&](int buf, int t){
    const int kv0 = kvbase + t * 64;
    #pragma unroll
    for (int i = 0; i < 4; ++i){          // K: 2048 16B chunks / 512 threads
      int c = i*512 + tid;
      int r = c >> 5, x = c & 31;
      gload16(Kg + (size_t)(kv0 + r)*H_ + ((x ^ (r & 7)) << 3),
              Kl0 + buf*16384 + (i*512 + (tid & ~63)) * 8);
    }
    #pragma unroll
    for (int i = 0; i < 4; ++i){          // Vt: 2048 16B chunks
      int c = i*512 + tid;
      int f = c >> 3, x = c & 7;
      gload16(Vg + (size_t)f*N_ + kv0 + ((x ^ (f & 7)) << 3),
              Vl0 + buf*16384 + (i*512 + (tid & ~63)) * 8);
    }
  };

  stage(0, 0);
  __syncthreads();

  const int krow = kvh*32 + q32;
  for (int t = 0; t < 32; ++t){
    const int cur = t & 1;
    if (t + 1 < 32) stage(cur ^ 1, t + 1);

    // ---- S^T = K Q^T : this wave's 32kv x 32q
    f32x16 s;
    #pragma unroll
    for (int e = 0; e < 16; ++e) s[e] = 0.f;
    const char* Kb = (const char*)(Kl0 + cur*16384);
    __builtin_amdgcn_s_setprio(1);
    #pragma unroll
    for (int ks = 0; ks < 16; ++ks){
      int cw = ks*2 + hi;
      f16x8 ka = *(const f16x8*)(Kb + krow*512 + ((cw ^ (krow & 7)) << 4));
      s = mfma32(ka, qf[ks], s);
    }
    __builtin_amdgcn_s_setprio(0);

    // ---- online softmax: lane owns one q-col; kv split lane<->lane^32
    float mloc = s[0];
    #pragma unroll
    for (int e = 1; e < 16; ++e) mloc = fmaxf(mloc, s[e]);
    float mx = fmaxf(mloc, __shfl_xor(mloc, 32));
    if (!__all(mx - m_run <= 8.0f)){
      float mn = fmaxf(m_run, mx);
      float al = __builtin_amdgcn_exp2f((m_run - mn) * L2E);
      m_run = mn; l_run *= al;
      #pragma unroll
      for (int ft = 0; ft < 8; ++ft)
        #pragma unroll
        for (int e = 0; e < 16; ++e) oacc[ft][e] *= al;
    }
    float ps = 0.f;
    #pragma unroll
    for (int e = 0; e < 16; ++e){
      float p = __builtin_amdgcn_exp2f((s[e] - m_run) * L2E);
      s[e] = p; ps += p;
    }
    l_run += ps + __shfl_xor(ps, 32);

    // ---- P -> B-frags in-register: s[reg] holds kv=(reg&3)+8*(reg>>2)+4*hi
    unsigned xw[4], yw[4];
    #pragma unroll
    for (int o = 0; o < 4; ++o){
      xw[o] = pkrtz(s[4*o],   s[4*o+1]);   // kv 8o+4hi+0,1
      yw[o] = pkrtz(s[4*o+2], s[4*o+3]);   // kv 8o+4hi+2,3
    }

    // ---- O^T += V^T P^T
    const char* Vb = (const char*)(Vl0 + cur*16384);
    #pragma unroll
    for (int ks2 = 0; ks2 < 2; ++ks2){
      unsigned a0 = xw[2*ks2], b0 = xw[2*ks2+1];
      unsigned c0 = yw[2*ks2], d0 = yw[2*ks2+1];
      unsigned sa = __shfl_xor(a0, 32), sb = __shfl_xor(b0, 32);
      unsigned sc = __shfl_xor(c0, 32), sd = __shfl_xor(d0, 32);
      union { unsigned u[4]; f16x8 v; } pa;
      pa.u[0] = hi ? sb : a0;   // k j0,1
      pa.u[1] = hi ? sd : c0;   // k j2,3
      pa.u[2] = hi ? b0 : sa;   // k j4,5
      pa.u[3] = hi ? d0 : sc;   // k j6,7
      __builtin_amdgcn_s_setprio(1);
      #pragma unroll
      for (int ft = 0; ft < 8; ++ft){
        int f  = ft*32 + q32;
        int cw = kvh*4 + ks2*2 + hi;
        f16x8 va = *(const f16x8*)(Vb + f*128 + ((cw ^ (f & 7)) << 4));
        oacc[ft] = mfma32(va, pa.v, oacc[ft]);
      }
      __builtin_amdgcn_s_setprio(0);
    }
    __syncthreads();   // drains vmcnt: next-tile stage complete
  }

  // ---- merge kv-halves within block (scratch reuses K/V LDS)
  __syncthreads();
  float* scr = (float*)lds;                // 4 strips x 32q x 256f f32 = 128KB
  if (kvh == 1){
    #pragma unroll
    for (int ft = 0; ft < 8; ++ft)
      #pragma unroll
      for (int rg = 0; rg < 4; ++rg){
        int c = 8*ft + 2*rg + hi;
        f32x4 v = { oacc[ft][4*rg], oacc[ft][4*rg+1],
                    oacc[ft][4*rg+2], oacc[ft][4*rg+3] };
        *(f32x4*)(scr + strip*8192 + q32*256 + (c ^ (q32 & 7))*4) = v;
      }
    if (hi == 0){ mlb[strip*32 + q32] = m_run; mlb[128 + strip*32 + q32] = l_run; }
  }
  __syncthreads();
  if (kvh == 0){
    float mB = mlb[strip*32 + q32], lB = mlb[128 + strip*32 + q32];
    float mM = fmaxf(m_run, mB);
    float e0 = __builtin_amdgcn_exp2f((m_run - mM) * L2E);
    float e1 = __builtin_amdgcn_exp2f((mB    - mM) * L2E);
    float lM = e0*l_run + e1*lB;
    float inv = 1.0f / lM;
    size_t row = (size_t)b*N_ + q0 + strip*32 + q32;
    f16* od = Opn + ((size_t)kb*BN_ + row) * H_;
    #pragma unroll
    for (int ft = 0; ft < 8; ++ft)
      #pragma unroll
      for (int rg = 0; rg < 4; ++rg){
        int c = 8*ft + 2*rg + hi;
        f32x4 vB = *(const f32x4*)(scr + strip*8192 + q32*256 + (c ^ (q32 & 7))*4);
        f16x4 hv;
        #pragma unroll
        for (int j = 0; j < 4; ++j)
          hv[j] = (f16)((e0*oacc[ft][4*rg+j] + e1*vB[j]) * inv);
        *(f16x4*)(od + 32*ft + 8*rg + 4*hi) = hv;
      }
    if (hi == 0) mll[(size_t)kb*BN_ + row] = mM*L2E + __log2f(lM);
  }
}

// Combine the two kv-split partials: out = (w0*O0n + w1*O1n)/(w0+w1)
__global__ __launch_bounds__(256) void merge_kernel(
    const f16* __restrict__ Opn, const float* __restrict__ mll,
    float* __restrict__ out){
  int i = blockIdx.x*256 + threadIdx.x;   // one 4-feature chunk
  int row = i >> 6, c = i & 63;
  float g0 = mll[row], g1 = mll[BN_ + row];
  float gm = fmaxf(g0, g1);
  float w0 = __builtin_amdgcn_exp2f(g0 - gm);
  float w1 = __builtin_amdgcn_exp2f(g1 - gm);
  float inv = 1.0f / (w0 + w1);
  f16x4 a  = *(const f16x4*)(Opn + (size_t)row*H_ + c*4);
  f16x4 bq = *(const f16x4*)(Opn + ((size_t)BN_ + row)*H_ + c*4);
  float4 o;
  o.x = (w0*(float)a[0] + w1*(float)bq[0]) * inv;
  o.y = (w0*(float)a[1] + w1*(float)bq[1]) * inv;
  o.z = (w0*(float)a[2] + w1*(float)bq[2]) * inv;
  o.w = (w0*(float)a[3] + w1*(float)bq[3]) * inv;
  *(float4*)(out + (size_t)row*H_ + c*4) = o;
}

extern "C" void kernel_launch(void* const* d_in, const int* in_sizes, int n_in,
                              void* d_out, int out_size, void* d_ws, size_t ws_size,
                              hipStream_t stream) {
  const float* x  = (const float*)d_in[0];
  const float* Wq = (const float*)d_in[1];
  const float* bq = (const float*)d_in[2];
  const float* Wk = (const float*)d_in[3];
  const float* bk = (const float*)d_in[4];
  const float* Wv = (const float*)d_in[5];
  const float* bv = (const float*)d_in[6];
  float* out = (float*)d_out;

  // workspace layout (~41 MB)
  char* ws = (char*)d_ws;
  const size_t SZ = (size_t)BN_ * H_ * 2;              // 8 MB
  f16*   qb  = (f16*)(ws);
  f16*   kb  = (f16*)(ws + SZ);
  f16*   vt  = (f16*)(ws + 2*SZ);                      // [B][H][N]
  f16*   opn = (f16*)(ws + 3*SZ);                      // [2][BN][H] f16 (16MB)
  float* mll = (float*)(ws + 5*SZ);                    // [2][BN] f32 (128KB)
  f16*   wqb = (f16*)(ws + 5*SZ + 131072);
  f16*   wkb = wqb + H_*H_;
  f16*   wvb = wkb + H_*H_;
  f16*   xb  = wvb + H_*H_;                            // x-f16 (8MB)

  cvt_f32_f16<<<(BN_*H_/4 + 255)/256, 256, 0, stream>>>(x,  xb,  BN_*H_/4);
  cvt_f32_f16<<<(H_*H_/4  + 255)/256, 256, 0, stream>>>(Wq, wqb, H_*H_/4);
  cvt_f32_f16<<<(H_*H_/4  + 255)/256, 256, 0, stream>>>(Wk, wkb, H_*H_/4);
  cvt_f32_f16<<<(H_*H_/4  + 255)/256, 256, 0, stream>>>(Wv, wvb, H_*H_/4);

  dim3 pgrid(BN_/64, H_/64);
  proj_kernel<0><<<pgrid, 256, 0, stream>>>(xb, wqb, bq, qb);
  proj_kernel<0><<<pgrid, 256, 0, stream>>>(xb, wkb, bk, kb);
  proj_kernel<1><<<pgrid, 256, 0, stream>>>(xb, wvb, bv, vt);

  flash_kernel<<<(BN_/128)*2, 512, 0, stream>>>(qb, kb, vt, opn, mll);
  merge_kernel<<<BN_*64/256, 256, 0, stream>>>(opn, mll, out);
}

// Round 6
// 123.105 us; speedup vs baseline: 2.1368x; 1.3862x over previous
//
#include <hip/hip_runtime.h>

#define B_ 4
#define N_ 4096
#define H_ 256
#define BN_ (B_*N_)
#define L2E 1.44269504088896340736f

typedef _Float16 f16;
typedef __fp16 fp16x2 __attribute__((ext_vector_type(2)));
typedef f16 f16x4 __attribute__((ext_vector_type(4)));
typedef f16 f16x8 __attribute__((ext_vector_type(8)));
typedef float f32x4 __attribute__((ext_vector_type(4)));
typedef float f32x16 __attribute__((ext_vector_type(16)));

static __device__ __forceinline__ f32x16 mfma32(f16x8 a, f16x8 b, f32x16 c){
  return __builtin_amdgcn_mfma_f32_32x32x16_f16(a, b, c, 0, 0, 0);
}
static __device__ __forceinline__ unsigned pkrtz(float a, float b){
  fp16x2 h = __builtin_amdgcn_cvt_pkrtz(a, b);
  return __builtin_bit_cast(unsigned, h);
}

// async global->LDS, 16B per lane; LDS dest is wave-uniform base + lane*16
static __device__ __forceinline__ void gload16(const void* g, void* l){
  __builtin_amdgcn_global_load_lds(
    (const __attribute__((address_space(1))) unsigned int*)g,
    (__attribute__((address_space(3))) unsigned int*)l, 16, 0, 0);
}

__global__ __launch_bounds__(256, 4) void cvt_f32_f16(
    const float* __restrict__ in, f16* __restrict__ out, int n4){
  int i = blockIdx.x * 256 + threadIdx.x;
  if (i < n4){
    float4 f = ((const float4*)in)[i];
    f16x4 o;
    o[0] = (f16)f.x; o[1] = (f16)f.y; o[2] = (f16)f.z; o[3] = (f16)f.w;
    ((f16x4*)out)[i] = o;
  }
}

// Convert 3 f32 weight matrices [256][256] into frag-ordered f16 layout:
// unit u13 = ((ot*16 + ks)*2 + hi)*32 + ol holds W[ot*32+ol][ks*16+hi*8 .. +8].
// A wave reading units base..base+63 (ks,hi fixed, ol 0..31, hi 0/1) gets 1KB contiguous.
__global__ __launch_bounds__(256) void cvt_w_frag(
    const float* __restrict__ W0, const float* __restrict__ W1,
    const float* __restrict__ W2, f16* __restrict__ Wf){
  int u = blockIdx.x * 256 + threadIdx.x;        // [0, 3*8192)
  int m = u >> 13, u13 = u & 8191;
  const float* W = (m == 0) ? W0 : ((m == 1) ? W1 : W2);
  int ol = u13 & 31, t = u13 >> 5;
  int hi = t & 1, ks = (t >> 1) & 15, ot = t >> 5;
  int o = ot*32 + ol;
  const float* s = W + o*256 + ks*16 + hi*8;
  float4 f0 = *(const float4*)s, f1 = *(const float4*)(s + 4);
  f16x8 v;
  v[0]=(f16)f0.x; v[1]=(f16)f0.y; v[2]=(f16)f0.z; v[3]=(f16)f0.w;
  v[4]=(f16)f1.x; v[5]=(f16)f1.y; v[6]=(f16)f1.z; v[7]=(f16)f1.w;
  *(f16x8*)(Wf + (size_t)u * 8) = v;
}

// Fused QKV projection. Block = 64 rows, 8 waves; wave w owns o-cols w*32..+31
// for all three matrices. x tile staged once to LDS (swizzled), A-frags shared
// by q/k/v MFMAs. W read via frag-ordered layout (coalesced 1KB wave reads).
// q,k row-major [M][H]; v transposed per batch [B][H][N].
__global__ __launch_bounds__(512, 2) void proj_qkv(
    const f16* __restrict__ X, const f16* __restrict__ Wf,
    const float* __restrict__ bq, const float* __restrict__ bk,
    const float* __restrict__ bv,
    f16* __restrict__ Yq, f16* __restrict__ Yk, f16* __restrict__ Yvt){
  __shared__ f16 Xl[64*256];    // 32KB
  const int tid = threadIdx.x, l = tid & 63, w = tid >> 6;
  const int ol = l & 31, hi = l >> 5;
  const int m0 = blockIdx.x * 64;

  #pragma unroll
  for (int i = 0; i < 4; ++i){           // 2048 16B chunks / 512 threads
    int c = i*512 + tid;
    int r = c >> 5, x = c & 31;
    gload16(X + (size_t)(m0 + r)*H_ + ((x ^ (r & 7)) << 3),
            Xl + (i*512 + (tid & ~63)) * 8);
  }
  __syncthreads();

  f32x16 aq[2], ak[2], av[2];
  #pragma unroll
  for (int ms = 0; ms < 2; ++ms)
    #pragma unroll
    for (int e = 0; e < 16; ++e){ aq[ms][e]=0.f; ak[ms][e]=0.f; av[ms][e]=0.f; }

  const char* Xb = (const char*)Xl;
  #pragma unroll
  for (int ks = 0; ks < 16; ++ks){
    int cw = ks*2 + hi;
    f16x8 a0 = *(const f16x8*)(Xb + ((     ol)*32 + (cw ^ (ol & 7))) * 16);
    f16x8 a1 = *(const f16x8*)(Xb + ((32 + ol)*32 + (cw ^ (ol & 7))) * 16);
    size_t wu = ((size_t)((w*16 + ks)*2 + hi))*256 + ol*8;   // f16 offset
    f16x8 wqf = *(const f16x8*)(Wf + wu);
    f16x8 wkf = *(const f16x8*)(Wf + 65536 + wu);
    f16x8 wvf = *(const f16x8*)(Wf + 131072 + wu);
    aq[0] = mfma32(a0, wqf, aq[0]);  aq[1] = mfma32(a1, wqf, aq[1]);
    ak[0] = mfma32(a0, wkf, ak[0]);  ak[1] = mfma32(a1, wkf, ak[1]);
    av[0] = mfma32(a0, wvf, av[0]);  av[1] = mfma32(a1, wvf, av[1]);
  }

  const int o = w*32 + ol;
  const float Bq = bq[o], Bk = bk[o], Bv = bv[o];
  const int bb = m0 >> 12;
  const int nn0 = m0 & (N_-1);
  #pragma unroll
  for (int ms = 0; ms < 2; ++ms){
    #pragma unroll
    for (int rg = 0; rg < 4; ++rg){
      int rbase = m0 + ms*32 + 8*rg + 4*hi;
      f16x4 pk;
      #pragma unroll
      for (int j = 0; j < 4; ++j){
        float vq = (ms ? aq[1][4*rg+j] : aq[0][4*rg+j]) + Bq;
        float vk = (ms ? ak[1][4*rg+j] : ak[0][4*rg+j]) + Bk;
        float vv = (ms ? av[1][4*rg+j] : av[0][4*rg+j]) + Bv;
        Yq[(size_t)(rbase + j)*H_ + o] = (f16)vq;
        Yk[(size_t)(rbase + j)*H_ + o] = (f16)vk;
        pk[j] = (f16)vv;
      }
      *(f16x4*)(Yvt + ((size_t)(bb*H_ + o))*N_ + nn0 + ms*32 + 8*rg + 4*hi) = pk;
    }
  }
}

// Flash attention, 32x32 MFMA, swapped operands, QBLK=128, kv-split x2.
// (unchanged from R5: 103us, MfmaUtil 28%)
__global__ __launch_bounds__(512, 2) void flash_kernel(
    const f16* __restrict__ Q, const f16* __restrict__ K,
    const f16* __restrict__ Vt, f16* __restrict__ Opn, float* __restrict__ mll){
  __shared__ __align__(16) char lds[132*1024];
  f16* Kl0 = (f16*)lds;                   // [2][64*256]  64KB
  f16* Vl0 = (f16*)(lds + 65536);         // [2][256*64]  64KB
  float* mlb = (float*)(lds + 131072);    // 256 floats

  const int tid = threadIdx.x, l = tid & 63, w = tid >> 6;
  const int q32 = l & 31, hi = l >> 5;
  const int strip = w & 3, kvh = w >> 2;
  const int qblk = blockIdx.x >> 1, kb = blockIdx.x & 1;
  const int b = qblk >> 5, qt = qblk & 31;
  const int q0 = qt * 128;
  const int kvbase = kb * 2048;
  const f16* Kg = K  + (size_t)b * N_ * H_;
  const f16* Vg = Vt + (size_t)b * H_ * N_;

  f16x8 qf[16];
  {
    const f16* qp = Q + ((size_t)b*N_ + q0 + strip*32 + q32) * H_ + hi*8;
    #pragma unroll
    for (int ks = 0; ks < 16; ++ks) qf[ks] = *(const f16x8*)(qp + ks*16);
  }

  f32x16 oacc[8];
  #pragma unroll
  for (int ft = 0; ft < 8; ++ft)
    #pragma unroll
    for (int e = 0; e < 16; ++e) oacc[ft][e] = 0.f;
  float m_run = -3.0e38f, l_run = 0.f;

  auto stage = [&](int buf, int t){
    const int kv0 = kvbase + t * 64;
    #pragma unroll
    for (int i = 0; i < 4; ++i){
      int c = i*512 + tid;
      int r = c >> 5, x = c & 31;
      gload16(Kg + (size_t)(kv0 + r)*H_ + ((x ^ (r & 7)) << 3),
              Kl0 + buf*16384 + (i*512 + (tid & ~63)) * 8);
    }
    #pragma unroll
    for (int i = 0; i < 4; ++i){
      int c = i*512 + tid;
      int f = c >> 3, x = c & 7;
      gload16(Vg + (size_t)f*N_ + kv0 + ((x ^ (f & 7)) << 3),
              Vl0 + buf*16384 + (i*512 + (tid & ~63)) * 8);
    }
  };

  stage(0, 0);
  __syncthreads();

  const int krow = kvh*32 + q32;
  for (int t = 0; t < 32; ++t){
    const int cur = t & 1;
    if (t + 1 < 32) stage(cur ^ 1, t + 1);

    f32x16 s;
    #pragma unroll
    for (int e = 0; e < 16; ++e) s[e] = 0.f;
    const char* Kb = (const char*)(Kl0 + cur*16384);
    __builtin_amdgcn_s_setprio(1);
    #pragma unroll
    for (int ks = 0; ks < 16; ++ks){
      int cw = ks*2 + hi;
      f16x8 ka = *(const f16x8*)(Kb + krow*512 + ((cw ^ (krow & 7)) << 4));
      s = mfma32(ka, qf[ks], s);
    }
    __builtin_amdgcn_s_setprio(0);

    float mloc = s[0];
    #pragma unroll
    for (int e = 1; e < 16; ++e) mloc = fmaxf(mloc, s[e]);
    float mx = fmaxf(mloc, __shfl_xor(mloc, 32));
    if (!__all(mx - m_run <= 8.0f)){
      float mn = fmaxf(m_run, mx);
      float al = __builtin_amdgcn_exp2f((m_run - mn) * L2E);
      m_run = mn; l_run *= al;
      #pragma unroll
      for (int ft = 0; ft < 8; ++ft)
        #pragma unroll
        for (int e = 0; e < 16; ++e) oacc[ft][e] *= al;
    }
    float ps = 0.f;
    #pragma unroll
    for (int e = 0; e < 16; ++e){
      float p = __builtin_amdgcn_exp2f((s[e] - m_run) * L2E);
      s[e] = p; ps += p;
    }
    l_run += ps + __shfl_xor(ps, 32);

    unsigned xw[4], yw[4];
    #pragma unroll
    for (int o = 0; o < 4; ++o){
      xw[o] = pkrtz(s[4*o],   s[4*o+1]);
      yw[o] = pkrtz(s[4*o+2], s[4*o+3]);
    }

    const char* Vb = (const char*)(Vl0 + cur*16384);
    #pragma unroll
    for (int ks2 = 0; ks2 < 2; ++ks2){
      unsigned a0 = xw[2*ks2], b0 = xw[2*ks2+1];
      unsigned c0 = yw[2*ks2], d0 = yw[2*ks2+1];
      unsigned sa = __shfl_xor(a0, 32), sb = __shfl_xor(b0, 32);
      unsigned sc = __shfl_xor(c0, 32), sd = __shfl_xor(d0, 32);
      union { unsigned u[4]; f16x8 v; } pa;
      pa.u[0] = hi ? sb : a0;
      pa.u[1] = hi ? sd : c0;
      pa.u[2] = hi ? b0 : sa;
      pa.u[3] = hi ? d0 : sc;
      __builtin_amdgcn_s_setprio(1);
      #pragma unroll
      for (int ft = 0; ft < 8; ++ft){
        int f  = ft*32 + q32;
        int cw = kvh*4 + ks2*2 + hi;
        f16x8 va = *(const f16x8*)(Vb + f*128 + ((cw ^ (f & 7)) << 4));
        oacc[ft] = mfma32(va, pa.v, oacc[ft]);
      }
      __builtin_amdgcn_s_setprio(0);
    }
    __syncthreads();
  }

  __syncthreads();
  float* scr = (float*)lds;
  if (kvh == 1){
    #pragma unroll
    for (int ft = 0; ft < 8; ++ft)
      #pragma unroll
      for (int rg = 0; rg < 4; ++rg){
        int c = 8*ft + 2*rg + hi;
        f32x4 v = { oacc[ft][4*rg], oacc[ft][4*rg+1],
                    oacc[ft][4*rg+2], oacc[ft][4*rg+3] };
        *(f32x4*)(scr + strip*8192 + q32*256 + (c ^ (q32 & 7))*4) = v;
      }
    if (hi == 0){ mlb[strip*32 + q32] = m_run; mlb[128 + strip*32 + q32] = l_run; }
  }
  __syncthreads();
  if (kvh == 0){
    float mB = mlb[strip*32 + q32], lB = mlb[128 + strip*32 + q32];
    float mM = fmaxf(m_run, mB);
    float e0 = __builtin_amdgcn_exp2f((m_run - mM) * L2E);
    float e1 = __builtin_amdgcn_exp2f((mB    - mM) * L2E);
    float lM = e0*l_run + e1*lB;
    float inv = 1.0f / lM;
    size_t row = (size_t)b*N_ + q0 + strip*32 + q32;
    f16* od = Opn + ((size_t)kb*BN_ + row) * H_;
    #pragma unroll
    for (int ft = 0; ft < 8; ++ft)
      #pragma unroll
      for (int rg = 0; rg < 4; ++rg){
        int c = 8*ft + 2*rg + hi;
        f32x4 vB = *(const f32x4*)(scr + strip*8192 + q32*256 + (c ^ (q32 & 7))*4);
        f16x4 hv;
        #pragma unroll
        for (int j = 0; j < 4; ++j)
          hv[j] = (f16)((e0*oacc[ft][4*rg+j] + e1*vB[j]) * inv);
        *(f16x4*)(od + 32*ft + 8*rg + 4*hi) = hv;
      }
    if (hi == 0) mll[(size_t)kb*BN_ + row] = mM*L2E + __log2f(lM);
  }
}

__global__ __launch_bounds__(256) void merge_kernel(
    const f16* __restrict__ Opn, const float* __restrict__ mll,
    float* __restrict__ out){
  int i = blockIdx.x*256 + threadIdx.x;
  int row = i >> 6, c = i & 63;
  float g0 = mll[row], g1 = mll[BN_ + row];
  float gm = fmaxf(g0, g1);
  float w0 = __builtin_amdgcn_exp2f(g0 - gm);
  float w1 = __builtin_amdgcn_exp2f(g1 - gm);
  float inv = 1.0f / (w0 + w1);
  f16x4 a  = *(const f16x4*)(Opn + (size_t)row*H_ + c*4);
  f16x4 bq = *(const f16x4*)(Opn + ((size_t)BN_ + row)*H_ + c*4);
  float4 o;
  o.x = (w0*(float)a[0] + w1*(float)bq[0]) * inv;
  o.y = (w0*(float)a[1] + w1*(float)bq[1]) * inv;
  o.z = (w0*(float)a[2] + w1*(float)bq[2]) * inv;
  o.w = (w0*(float)a[3] + w1*(float)bq[3]) * inv;
  *(float4*)(out + (size_t)row*H_ + c*4) = o;
}

extern "C" void kernel_launch(void* const* d_in, const int* in_sizes, int n_in,
                              void* d_out, int out_size, void* d_ws, size_t ws_size,
                              hipStream_t stream) {
  const float* x  = (const float*)d_in[0];
  const float* Wq = (const float*)d_in[1];
  const float* bq = (const float*)d_in[2];
  const float* Wk = (const float*)d_in[3];
  const float* bk = (const float*)d_in[4];
  const float* Wv = (const float*)d_in[5];
  const float* bv = (const float*)d_in[6];
  float* out = (float*)d_out;

  // workspace layout (~49 MB)
  char* ws = (char*)d_ws;
  const size_t SZ = (size_t)BN_ * H_ * 2;              // 8 MB
  f16*   qb  = (f16*)(ws);
  f16*   kb  = (f16*)(ws + SZ);
  f16*   vt  = (f16*)(ws + 2*SZ);                      // [B][H][N]
  f16*   opn = (f16*)(ws + 3*SZ);                      // [2][BN][H] f16 (16MB)
  float* mll = (float*)(ws + 5*SZ);                    // [2][BN] f32 (128KB)
  f16*   wf  = (f16*)(ws + 5*SZ + 131072);             // fragged W [3][65536] f16 (384KB)
  f16*   xb  = (f16*)(ws + 5*SZ + 131072 + 393216);    // x-f16 (8MB)

  cvt_f32_f16<<<(BN_*H_/4 + 255)/256, 256, 0, stream>>>(x, xb, BN_*H_/4);
  cvt_w_frag<<<96, 256, 0, stream>>>(Wq, Wk, Wv, wf);
  proj_qkv<<<BN_/64, 512, 0, stream>>>(xb, wf, bq, bk, bv, qb, kb, vt);
  flash_kernel<<<(BN_/128)*2, 512, 0, stream>>>(qb, kb, vt, opn, mll);
  merge_kernel<<<BN_*64/256, 256, 0, stream>>>(opn, mll, out);
}